// Round 1
// baseline (132.544 us; speedup 1.0000x reference)
//
#include <hip/hip_runtime.h>
#include <hip/hip_bf16.h>

// out[i] = y[i] * w[idx] + b[idx]
// idx = (t[i] << 10) | sum_j x[i][j] << (9 - j)   (t is the MSB)
// N = 2,000,000 rows, INPUT_DIM = 10, C = 2048.
// Memory-bound: ~104 MB total traffic -> ~16.5 us floor at 6.3 TB/s.

#define INPUT_DIM 10

__global__ __launch_bounds__(256) void enc_kernel(
    const float* __restrict__ x,   // [N,10] binary 0/1
    const float* __restrict__ t,   // [N,1] binary 0/1
    const float* __restrict__ y,   // [N,1]
    const float* __restrict__ w,   // [2048]
    const float* __restrict__ b,   // [2048]
    float* __restrict__ out,       // [N,1]
    int n)
{
    int i = blockIdx.x * blockDim.x + threadIdx.x;
    if (i >= n) return;

    // Row base is 40 B -> always 8B-aligned, never 16B-aligned for odd rows.
    // Use five float2 loads; a wave's accesses cover one contiguous 2560B span.
    const float2* xr = (const float2*)(x + (size_t)i * INPUT_DIM);
    float2 a0 = xr[0];
    float2 a1 = xr[1];
    float2 a2 = xr[2];
    float2 a3 = xr[3];
    float2 a4 = xr[4];

    int idx = ((int)t[i]) << 10;
    idx |= ((int)a0.x << 9) | ((int)a0.y << 8)
         | ((int)a1.x << 7) | ((int)a1.y << 6)
         | ((int)a2.x << 5) | ((int)a2.y << 4)
         | ((int)a3.x << 3) | ((int)a3.y << 2)
         | ((int)a4.x << 1) | ((int)a4.y);

    // w/b tables are 8 KB each -> resident in L1/L2; direct gather.
    out[i] = fmaf(y[i], w[idx], b[idx]);
}

extern "C" void kernel_launch(void* const* d_in, const int* in_sizes, int n_in,
                              void* d_out, int out_size, void* d_ws, size_t ws_size,
                              hipStream_t stream) {
    const float* x = (const float*)d_in[0];
    const float* t = (const float*)d_in[1];
    const float* y = (const float*)d_in[2];
    const float* w = (const float*)d_in[3];
    const float* b = (const float*)d_in[4];
    float* out = (float*)d_out;

    int n = out_size;  // 2,000,000 rows
    int block = 256;
    int grid = (n + block - 1) / block;
    enc_kernel<<<grid, block, 0, stream>>>(x, t, y, w, b, out, n);
}